// Round 5
// baseline (1240.158 us; speedup 1.0000x reference)
//
#include <hip/hip_runtime.h>

#define D_  1024
#define FF_ 4096
#define H_  16
#define DH_ 64
#define B_  2
#define S_  2048
#define M_  4096   // B_*S_

typedef __attribute__((ext_vector_type(8))) __bf16 bf16x8;
typedef __attribute__((ext_vector_type(4))) short short4v;
typedef __attribute__((ext_vector_type(4))) float floatx4;

typedef __attribute__((address_space(1))) unsigned int as1_uint;
typedef __attribute__((address_space(3))) unsigned int as3_uint;

__device__ __forceinline__ unsigned short f2bf(float f) {
    unsigned u = __float_as_uint(f);
    u += 0x7FFFu + ((u >> 16) & 1u);   // round-to-nearest-even
    return (unsigned short)(u >> 16);
}

// pack high halves of two f32 (truncation) -> bf16 pair in one dword
__device__ __forceinline__ int packbf(float a, float b) {
    return (int)((__float_as_uint(a) >> 16) | (__float_as_uint(b) & 0xFFFF0000u));
}

// async global->LDS, 16B per lane (wave-uniform base + lane*16)
__device__ __forceinline__ void gl_lds16(const void* g, void* l) {
    __builtin_amdgcn_global_load_lds((as1_uint*)(unsigned long long)g,
                                     (as3_uint*)l, 16, 0, 0);
}

// ---------------------------------------------------------------------------
// Batched weight convert+transpose: 6 weights per layer in ONE launch.
// Each: src f32 [K,N] -> dst bf16 [N,K], 32x32 tiles.
// ---------------------------------------------------------------------------
struct TDesc { const float* src; unsigned short* dst; int K; int N; int ntx; };
struct TPack { TDesc d[6]; int cum[7]; };

__global__ __launch_bounds__(256) void transpose_cvt_batch(TPack p)
{
    __shared__ float tile[32][33];
    int bid = blockIdx.x;
    int seg = 0;
    while (bid >= p.cum[seg + 1]) ++seg;
    const TDesc d = p.d[seg];
    const int t = bid - p.cum[seg];
    const int n0 = (t % d.ntx) * 32, k0 = (t / d.ntx) * 32;
    const int tx = threadIdx.x, ty = threadIdx.y;
#pragma unroll
    for (int i = 0; i < 32; i += 8)
        tile[ty + i][tx] = d.src[(size_t)(k0 + ty + i) * d.N + n0 + tx];
    __syncthreads();
#pragma unroll
    for (int i = 0; i < 32; i += 8)
        d.dst[(size_t)(n0 + ty + i) * d.K + k0 + tx] = f2bf(tile[tx][ty + i]);
}

// ---------------------------------------------------------------------------
// V [BH][S][DH] bf16 -> VT [BH][DH][S] bf16 (64-s tiles)
// ---------------------------------------------------------------------------
__global__ __launch_bounds__(256) void transpose_v(
    const unsigned short* __restrict__ V, unsigned short* __restrict__ VT)
{
    __shared__ unsigned short t[64][72];
    const int bh = blockIdx.y, s0 = blockIdx.x * 64;
    const int tid = threadIdx.x;
#pragma unroll
    for (int i = 0; i < 2; i++) {
        int u = tid + i * 256;
        int s = u >> 3, dc = u & 7;
        uint4 v = *(const uint4*)(V + ((size_t)bh * S_ + s0 + s) * DH_ + dc * 8);
        *(uint4*)&t[s][dc * 8] = v;
    }
    __syncthreads();
    const int dh = tid >> 2, sc = (tid & 3) * 16;
    unsigned v[16];
#pragma unroll
    for (int j = 0; j < 16; j++) v[j] = t[sc + j][dh];
    uint4 o0, o1;
    o0.x = v[0] | (v[1] << 16);  o0.y = v[2] | (v[3] << 16);
    o0.z = v[4] | (v[5] << 16);  o0.w = v[6] | (v[7] << 16);
    o1.x = v[8] | (v[9] << 16);  o1.y = v[10] | (v[11] << 16);
    o1.z = v[12] | (v[13] << 16); o1.w = v[14] | (v[15] << 16);
    unsigned short* dst = VT + ((size_t)bh * DH_ + dh) * S_ + s0 + sc;
    *(uint4*)dst = o0;
    *(uint4*)(dst + 8) = o1;
}

// ---------------------------------------------------------------------------
// x0: f32 -> (f32 copy, bf16 copy)
// ---------------------------------------------------------------------------
__global__ __launch_bounds__(256) void cvt_x0(
    const float* __restrict__ in, float* __restrict__ xf, unsigned short* __restrict__ xh)
{
    int i = blockIdx.x * 256 + threadIdx.x;
    float4 v = ((const float4*)in)[i];
    ((float4*)xf)[i] = v;
    uint2 h;
    h.x = (unsigned)f2bf(v.x) | ((unsigned)f2bf(v.y) << 16);
    h.y = (unsigned)f2bf(v.z) | ((unsigned)f2bf(v.w) << 16);
    ((uint2*)xh)[i] = h;
}

// ---------------------------------------------------------------------------
// Unified GEMM: 128x128 tile, BK=64, XOR-swizzled LDS, optional split-K.
//  EPI 0: f32 partial (no bias); z<2 -> outF + z*M*N, z>=2 -> outF2 + (z&1)*M*N
//  EPI 1: bf16 + bias + relu -> outH              [FFN1]
//  EPI 2: QKV scatter to [B,H,S,DH] bf16, Q pre-scaled by log2e/8
// ---------------------------------------------------------------------------
template <int EPI, int KSPLIT>
__global__ __launch_bounds__(256) void gemm128(
    const unsigned short* __restrict__ A, const unsigned short* __restrict__ BT,
    int M, int N, int K,
    const float* __restrict__ b0, const float* __restrict__ b1, const float* __restrict__ b2,
    float* __restrict__ outF, float* __restrict__ outF2, unsigned short* __restrict__ outH,
    unsigned short* __restrict__ qO, unsigned short* __restrict__ kO, unsigned short* __restrict__ vO)
{
    __shared__ __align__(16) unsigned short As[128 * 64];   // 16 KB
    __shared__ __align__(16) unsigned short Bs[128 * 64];   // 16 KB

    const int tid = threadIdx.x;
    const int m0 = blockIdx.y * 128, n0 = blockIdx.x * 128;
    const int kchunk = K / KSPLIT;
    const int kbase = (KSPLIT > 1) ? (int)blockIdx.z * kchunk : 0;
    const int lane = tid & 63, wv = tid >> 6;
    const int wm = wv & 1, wn = wv >> 1;
    const int cl = lane & 15, quad = lane >> 4;

    // staging: thread t -> rows (t>>3)+32i, slot t&7, global chunk slot^(row&7)
    const int srow = tid >> 3, sslot = tid & 7;
    const int schk = sslot ^ (srow & 7);
    const unsigned short* gA = A  + (size_t)(m0 + srow) * K + kbase + schk * 8;
    const unsigned short* gB = BT + (size_t)(n0 + srow) * K + kbase + schk * 8;

    floatx4 acc[4][4];
#pragma unroll
    for (int i = 0; i < 4; i++)
#pragma unroll
        for (int j = 0; j < 4; j++) acc[i][j] = (floatx4){0.f, 0.f, 0.f, 0.f};

    for (int kt = 0; kt < kchunk; kt += 64) {
#pragma unroll
        for (int i = 0; i < 4; i++) {
            gl_lds16(gA + (size_t)(32 * i) * K + kt, &As[(size_t)(tid + 256 * i) * 8]);
            gl_lds16(gB + (size_t)(32 * i) * K + kt, &Bs[(size_t)(tid + 256 * i) * 8]);
        }
        __syncthreads();

        bf16x8 av[4][2], bv[4][2];
#pragma unroll
        for (int mi = 0; mi < 4; mi++) {
            const int row = wm * 64 + mi * 16 + cl;
#pragma unroll
            for (int ks = 0; ks < 2; ks++)
                av[mi][ks] = *(const bf16x8*)&As[row * 64 + (((ks * 4 + quad) ^ (cl & 7)) * 8)];
        }
#pragma unroll
        for (int ni = 0; ni < 4; ni++) {
            const int row = wn * 64 + ni * 16 + cl;
#pragma unroll
            for (int ks = 0; ks < 2; ks++)
                bv[ni][ks] = *(const bf16x8*)&Bs[row * 64 + (((ks * 4 + quad) ^ (cl & 7)) * 8)];
        }
#pragma unroll
        for (int mi = 0; mi < 4; mi++)
#pragma unroll
            for (int ni = 0; ni < 4; ni++) {
                acc[mi][ni] = __builtin_amdgcn_mfma_f32_16x16x32_bf16(
                    av[mi][0], bv[ni][0], acc[mi][ni], 0, 0, 0);
                acc[mi][ni] = __builtin_amdgcn_mfma_f32_16x16x32_bf16(
                    av[mi][1], bv[ni][1], acc[mi][ni], 0, 0, 0);
            }
        __syncthreads();
    }

    float* outFz = nullptr;
    if (EPI == 0) {
        const int z = (KSPLIT > 1) ? (int)blockIdx.z : 0;
        outFz = ((z < 2) ? outF : outF2) + (size_t)(z & 1) * M * N;
    }
#pragma unroll
    for (int mi = 0; mi < 4; mi++) {
#pragma unroll
        for (int ni = 0; ni < 4; ni++) {
            const int c = n0 + wn * 64 + ni * 16 + cl;
#pragma unroll
            for (int r = 0; r < 4; r++) {
                const int rr = m0 + wm * 64 + mi * 16 + quad * 4 + r;
                float v = acc[mi][ni][r];
                if (EPI == 0) {
                    outFz[(size_t)rr * N + c] = v;        // partial, bias in LN
                } else if (EPI == 1) {
                    float t = v + b0[c];
                    outH[(size_t)rr * N + c] = f2bf(t > 0.f ? t : 0.f);
                } else {
                    const int kind = c >> 10, cc = c & 1023;
                    const float* bp = (kind == 0) ? b0 : (kind == 1) ? b1 : b2;
                    float t = v + bp[cc];
                    if (kind == 0) t *= 0.18033688f;   // log2e / 8
                    const int h = cc >> 6, dh = cc & 63;
                    const int bb = rr >> 11, s = rr & 2047;
                    unsigned short* dst = (kind == 0) ? qO : (kind == 1) ? kO : vO;
                    dst[((size_t)(bb * H_ + h) * S_ + s) * DH_ + dh] = f2bf(t);
                }
            }
        }
    }
}

// ---------------------------------------------------------------------------
// Flash attention v4: S^T orientation, single-pass softmax, DOUBLE-BUFFERED
// LDS. One barrier per 64-k tile: stage(t+1) issues right after the barrier,
// so compute(t) shadows the global->LDS latency; the barrier drain pays only
// the residual (unlike the 2-barrier structure where stage+drain is serial).
// ---------------------------------------------------------------------------
__global__ __launch_bounds__(256) void attn_kernel(
    const unsigned short* __restrict__ Qg, const unsigned short* __restrict__ Kg,
    const unsigned short* __restrict__ VTg, unsigned short* __restrict__ ctx)
{
    __shared__ __align__(16) unsigned short Ks[2][64 * 64];
    __shared__ __align__(16) unsigned short Vs[2][64 * 64];

    const int tid = threadIdx.x, lane = tid & 63, wv = tid >> 6;
    const int cl = lane & 15, quad = lane >> 4;

    // XCD-aware mapping: same-XCD blocks share 4 bh -> KV fits that XCD's L2
    const int lin = blockIdx.x;
    const int idx = lin >> 3;
    const int bh  = (lin & 7) * 4 + (idx & 3);
    const int qt  = idx >> 2;
    const int qrow = qt * 64 + wv * 16 + cl;
    const size_t bhS = (size_t)bh * S_;

    bf16x8 aq[2];
#pragma unroll
    for (int ks = 0; ks < 2; ks++)
        aq[ks] = *(const bf16x8*)(Qg + (bhS + qrow) * DH_ + ks * 32 + quad * 8);

    floatx4 O[4];
#pragma unroll
    for (int i = 0; i < 4; i++) O[i] = (floatx4){0.f, 0.f, 0.f, 0.f};
    float l_cur = 0.f;

    // staging granule g: row = g>>3, chunk = (g&7) ^ (row&7)  (XOR swizzle)
    const int g0 = tid, g1 = tid + 256;
    const int r_0 = g0 >> 3, c_0 = (g0 & 7) ^ (r_0 & 7);
    const int r_1 = g1 >> 3, c_1 = (g1 & 7) ^ (r_1 & 7);
    const unsigned short* kp0 = Kg + (bhS + r_0) * DH_ + c_0 * 8;
    const unsigned short* kp1 = Kg + (bhS + r_1) * DH_ + c_1 * 8;
    const unsigned short* vp0 = VTg + ((size_t)bh * DH_ + r_0) * S_ + c_0 * 8;
    const unsigned short* vp1 = VTg + ((size_t)bh * DH_ + r_1) * S_ + c_1 * 8;

    // tile-invariant fragment offsets (elements)
    int koff0[4], koff1[4], voff[4][4];
#pragma unroll
    for (int mi = 0; mi < 4; mi++) {
        const int row = mi * 16 + cl;
        koff0[mi] = (row * 8 + (quad       ^ (cl & 7))) * 8;
        koff1[mi] = (row * 8 + ((4 + quad) ^ (cl & 7))) * 8;
#pragma unroll
        for (int c16 = 0; c16 < 4; c16++) {
            const int slot = (c16 * 2 + (quad >> 1)) ^ (cl & 7);
            voff[c16][mi] = (row * 8 + slot) * 8 + (quad & 1) * 4;
        }
    }

    // prologue: stage tile 0 into buffer 0
    gl_lds16(kp0, &Ks[0][(size_t)g0 * 8]);
    gl_lds16(kp1, &Ks[0][(size_t)g1 * 8]);
    gl_lds16(vp0, &Vs[0][(size_t)g0 * 8]);
    gl_lds16(vp1, &Vs[0][(size_t)g1 * 8]);

    for (int t = 0; t < S_ / 64; t++) {
        __syncthreads();   // drains stage(t) loads; all waves done reading buf t-1
        if (t < S_ / 64 - 1) {
            const int k0n = (t + 1) * 64;
            const int bn = (t + 1) & 1;
            gl_lds16(kp0 + (size_t)k0n * DH_, &Ks[bn][(size_t)g0 * 8]);
            gl_lds16(kp1 + (size_t)k0n * DH_, &Ks[bn][(size_t)g1 * 8]);
            gl_lds16(vp0 + k0n, &Vs[bn][(size_t)g0 * 8]);
            gl_lds16(vp1 + k0n, &Vs[bn][(size_t)g1 * 8]);
        }
        const unsigned short* Kb = Ks[t & 1];
        const unsigned short* Vb = Vs[t & 1];

        // ---- St = K·Q^T : sc[mi][r] = score(k = t*64+mi*16+quad*4+r, q = qrow)
        floatx4 sc[4];
#pragma unroll
        for (int mi = 0; mi < 4; mi++) {
            bf16x8 kf0 = *(const bf16x8*)&Kb[koff0[mi]];
            bf16x8 kf1 = *(const bf16x8*)&Kb[koff1[mi]];
            floatx4 z = (floatx4){0.f, 0.f, 0.f, 0.f};
            z = __builtin_amdgcn_mfma_f32_16x16x32_bf16(kf0, aq[0], z, 0, 0, 0);
            sc[mi] = __builtin_amdgcn_mfma_f32_16x16x32_bf16(kf1, aq[1], z, 0, 0, 0);
        }

        // ---- single-pass softmax numerator: p = exp2(s); l accumulates per-lane
        int pk[4][2];
#pragma unroll
        for (int mi = 0; mi < 4; mi++) {
            float p0 = __builtin_amdgcn_exp2f(sc[mi][0]);
            float p1 = __builtin_amdgcn_exp2f(sc[mi][1]);
            float p2 = __builtin_amdgcn_exp2f(sc[mi][2]);
            float p3 = __builtin_amdgcn_exp2f(sc[mi][3]);
            l_cur += (p0 + p1) + (p2 + p3);
            pk[mi][0] = packbf(p0, p1);
            pk[mi][1] = packbf(p2, p3);
        }

        // ---- PV: O[dh][q] += V^T · P   (p fed straight from registers)
#pragma unroll
        for (int c16 = 0; c16 < 4; c16++) {
            union { int i[2]; short4v s; } pb;
            pb.i[0] = pk[c16][0];
            pb.i[1] = pk[c16][1];
#pragma unroll
            for (int mi2 = 0; mi2 < 4; mi2++) {
                short4v va = *(const short4v*)&Vb[voff[c16][mi2]];
                O[mi2] = __builtin_amdgcn_mfma_f32_16x16x16bf16_1k(va, pb.s, O[mi2], 0, 0, 0);
            }
        }
    }

    // final cross-quad reduction of l (lanes with same cl share the q row)
    l_cur += __shfl_xor(l_cur, 16);
    l_cur += __shfl_xor(l_cur, 32);

    const float invl = 1.f / l_cur;
    const int b = bh >> 4, h = bh & 15;
    unsigned short* cp = ctx + ((size_t)(b * S_ + qrow)) * D_ + h * DH_ + quad * 4;
#pragma unroll
    for (int mi2 = 0; mi2 < 4; mi2++) {
        unsigned short w[4];
#pragma unroll
        for (int r = 0; r < 4; r++) w[r] = f2bf(O[mi2][r] * invl);
        unsigned o0 = (unsigned)w[0] | ((unsigned)w[1] << 16);
        unsigned o1 = (unsigned)w[2] | ((unsigned)w[3] << 16);
        uint2 ov; ov.x = o0; ov.y = o1;
        *(uint2*)(cp + mi2 * 16) = ov;
    }
}

// ---------------------------------------------------------------------------
// Fused split-K reduce + bias + residual + LayerNorm.
// Partials: p<2 at t + p*M*N; p>=2 at t2 + (p-2)*M*N.
// ---------------------------------------------------------------------------
template <int NP>
__global__ __launch_bounds__(256) void ln_kernel(
    const float* __restrict__ t, const float* __restrict__ t2,
    const float* __restrict__ bias, const float* __restrict__ xr,
    const float* __restrict__ g, const float* __restrict__ b,
    float* __restrict__ xf, unsigned short* __restrict__ xh, float* __restrict__ extra)
{
    const int row = blockIdx.x, tid = threadIdx.x;
    float4 a = ((const float4*)(t + (size_t)row * D_))[tid];
#pragma unroll
    for (int p = 1; p < NP; p++) {
        const float* src = ((p < 2) ? t : t2) + (size_t)(p & 1) * M_ * D_;
        const float4 ap = ((const float4*)(src + (size_t)row * D_))[tid];
        a.x += ap.x; a.y += ap.y; a.z += ap.z; a.w += ap.w;
    }
    const float4 bs = ((const float4*)bias)[tid];
    const float4 c = ((const float4*)(xr + (size_t)row * D_))[tid];
    float4 y;
    y.x = a.x + bs.x + c.x; y.y = a.y + bs.y + c.y;
    y.z = a.z + bs.z + c.z; y.w = a.w + bs.w + c.w;
    float s  = y.x + y.y + y.z + y.w;
    float sq = y.x * y.x + y.y * y.y + y.z * y.z + y.w * y.w;
#pragma unroll
    for (int off = 1; off < 64; off <<= 1) {
        s  += __shfl_xor(s, off);
        sq += __shfl_xor(sq, off);
    }
    __shared__ float red[8];
    const int wv = tid >> 6, lane = tid & 63;
    if (lane == 0) { red[wv] = s; red[4 + wv] = sq; }
    __syncthreads();
    s  = red[0] + red[1] + red[2] + red[3];
    sq = red[4] + red[5] + red[6] + red[7];
    const float mean = s * (1.f / D_);
    const float var  = sq * (1.f / D_) - mean * mean;
    const float ri   = rsqrtf(var + 1e-6f);
    const float4 gg = ((const float4*)g)[tid];
    const float4 bb = ((const float4*)b)[tid];
    float4 o;
    o.x = (y.x - mean) * ri * gg.x + bb.x;
    o.y = (y.y - mean) * ri * gg.y + bb.y;
    o.z = (y.z - mean) * ri * gg.z + bb.z;
    o.w = (y.w - mean) * ri * gg.w + bb.w;
    ((float4*)(xf + (size_t)row * D_))[tid] = o;
    uint2 h;
    h.x = (unsigned)f2bf(o.x) | ((unsigned)f2bf(o.y) << 16);
    h.y = (unsigned)f2bf(o.z) | ((unsigned)f2bf(o.w) << 16);
    ((uint2*)(xh + (size_t)row * D_))[tid] = h;
    if (extra) ((float4*)(extra + (size_t)row * D_))[tid] = o;
}

// ---------------------------------------------------------------------------
extern "C" void kernel_launch(void* const* d_in, const int* in_sizes, int n_in,
                              void* d_out, int out_size, void* d_ws, size_t ws_size,
                              hipStream_t stream)
{
    const float* hs  = (const float*)d_in[0];
    const float* Wq  = (const float*)d_in[1];
    const float* bq  = (const float*)d_in[2];
    const float* Wk  = (const float*)d_in[3];
    const float* bk  = (const float*)d_in[4];
    const float* Wv  = (const float*)d_in[5];
    const float* bv  = (const float*)d_in[6];
    const float* Wp  = (const float*)d_in[7];
    const float* bp  = (const float*)d_in[8];
    const float* g1  = (const float*)d_in[9];
    const float* be1 = (const float*)d_in[10];
    const float* W1  = (const float*)d_in[11];
    const float* b1  = (const float*)d_in[12];
    const float* W2  = (const float*)d_in[13];
    const float* b2  = (const float*)d_in[14];
    const float* g2  = (const float*)d_in[15];
    const float* be2 = (const float*)d_in[16];

    char* w = (char*)d_ws;
    auto alloc = [&](size_t bytes) { char* p = w; w += (bytes + 255) & ~(size_t)255; return p; };
    unsigned short* wqkvT = (unsigned short*)alloc(3072ull * 1024 * 2);
    unsigned short* wpT   = (unsigned short*)alloc(1024ull * 1024 * 2);
    unsigned short* w1T   = (unsigned short*)alloc(4096ull * 1024 * 2);
    unsigned short* w2T   = (unsigned short*)alloc(1024ull * 4096 * 2);
    float*          xf    = (float*)alloc(4096ull * 1024 * 4);
    unsigned short* xh    = (unsigned short*)alloc(4096ull * 1024 * 2);
    unsigned short* qb_   = (unsigned short*)alloc(4096ull * 1024 * 2);
    unsigned short* kb_   = (unsigned short*)alloc(4096ull * 1024 * 2);
    unsigned short* vb_   = (unsigned short*)alloc(4096ull * 1024 * 2);
    unsigned short* ctx   = (unsigned short*)alloc(4096ull * 1024 * 2);
    float*          part  = (float*)alloc(2ull * 4096 * 1024 * 4);   // partials 0,1
    unsigned short* hh    = (unsigned short*)alloc(4096ull * 4096 * 2);
    unsigned short* vtb   = hh;                 // V^T scratch (hh free during attn)
    float*          part2 = (float*)qb_;        // partials 2,3 (qkv/ctx dead at FFN2)

    const dim3 blk(256);
    const dim3 tb(32, 8);

    cvt_x0<<<4096, blk, 0, stream>>>(hs, xf, xh);

    for (int l = 0; l < 4; l++) {
        // --- all 6 weight transposes in one launch ---
        TPack tp;
        tp.d[0] = { Wq + (size_t)l * D_ * D_,  wqkvT,                   D_,  D_,  32 };
        tp.d[1] = { Wk + (size_t)l * D_ * D_,  wqkvT + 1024 * 1024,     D_,  D_,  32 };
        tp.d[2] = { Wv + (size_t)l * D_ * D_,  wqkvT + 2 * 1024 * 1024, D_,  D_,  32 };
        tp.d[3] = { Wp + (size_t)l * D_ * D_,  wpT,                     D_,  D_,  32 };
        tp.d[4] = { W1 + (size_t)l * D_ * FF_, w1T,                     D_,  FF_, 128 };
        tp.d[5] = { W2 + (size_t)l * FF_ * D_, w2T,                     FF_, D_,  32 };
        tp.cum[0] = 0;    tp.cum[1] = 1024; tp.cum[2] = 2048; tp.cum[3] = 3072;
        tp.cum[4] = 4096; tp.cum[5] = 8192; tp.cum[6] = 12288;
        transpose_cvt_batch<<<12288, tb, 0, stream>>>(tp);

        // QKV: N=3072, K=1024
        gemm128<2, 1><<<dim3(24, 32), blk, 0, stream>>>(xh, wqkvT, M_, 3 * D_, D_,
            bq + l * D_, bk + l * D_, bv + l * D_,
            nullptr, nullptr, nullptr, qb_, kb_, vb_);

        transpose_v<<<dim3(32, 32), blk, 0, stream>>>(vb_, vtb);

        attn_kernel<<<1024, blk, 0, stream>>>(qb_, kb_, vtb, ctx);

        // proj: N=1024, K=1024, split-K x2 -> partials, reduced in LN1
        gemm128<0, 2><<<dim3(8, 32, 2), blk, 0, stream>>>(ctx, wpT, M_, D_, D_,
            nullptr, nullptr, nullptr, part, part, nullptr, nullptr, nullptr, nullptr);

        ln_kernel<2><<<4096, blk, 0, stream>>>(part, part, bp + l * D_, xf,
            g1 + l * D_, be1 + l * D_, xf, xh, nullptr);

        // FFN1: N=4096, K=1024
        gemm128<1, 1><<<dim3(32, 32), blk, 0, stream>>>(xh, w1T, M_, FF_, D_,
            b1 + l * FF_, nullptr, nullptr, nullptr, nullptr, hh, nullptr, nullptr, nullptr);

        // FFN2: N=1024, K=4096, split-K x4 -> partials 0,1 in part / 2,3 in part2
        gemm128<0, 4><<<dim3(8, 32, 4), blk, 0, stream>>>(hh, w2T, M_, D_, FF_,
            nullptr, nullptr, nullptr, part, part2, nullptr, nullptr, nullptr, nullptr);

        ln_kernel<4><<<4096, blk, 0, stream>>>(part, part2, b2 + l * D_, xf,
            g2 + l * D_, be2 + l * D_, xf, xh,
            (l == 3) ? (float*)d_out : nullptr);
    }
}

// Round 6
// 1219.372 us; speedup vs baseline: 1.0170x; 1.0170x over previous
//
#include <hip/hip_runtime.h>

#define D_  1024
#define FF_ 4096
#define H_  16
#define DH_ 64
#define B_  2
#define S_  2048
#define M_  4096   // B_*S_

typedef __attribute__((ext_vector_type(8))) __bf16 bf16x8;
typedef __attribute__((ext_vector_type(4))) short short4v;
typedef __attribute__((ext_vector_type(4))) float floatx4;

typedef __attribute__((address_space(1))) unsigned int as1_uint;
typedef __attribute__((address_space(3))) unsigned int as3_uint;

__device__ __forceinline__ unsigned short f2bf(float f) {
    unsigned u = __float_as_uint(f);
    u += 0x7FFFu + ((u >> 16) & 1u);   // round-to-nearest-even
    return (unsigned short)(u >> 16);
}

// pack high halves of two f32 (truncation) -> bf16 pair in one dword
__device__ __forceinline__ int packbf(float a, float b) {
    return (int)((__float_as_uint(a) >> 16) | (__float_as_uint(b) & 0xFFFF0000u));
}

// async global->LDS, 16B per lane (wave-uniform base + lane*16)
__device__ __forceinline__ void gl_lds16(const void* g, void* l) {
    __builtin_amdgcn_global_load_lds((as1_uint*)(unsigned long long)g,
                                     (as3_uint*)l, 16, 0, 0);
}

// ---------------------------------------------------------------------------
// Batched weight convert+transpose: 6 weights per layer in ONE launch.
// Each: src f32 [K,N] -> dst bf16 [N,K], 32x32 tiles.
// ---------------------------------------------------------------------------
struct TDesc { const float* src; unsigned short* dst; int K; int N; int ntx; };
struct TPack { TDesc d[6]; int cum[7]; };

__global__ __launch_bounds__(256) void transpose_cvt_batch(TPack p)
{
    __shared__ float tile[32][33];
    int bid = blockIdx.x;
    int seg = 0;
    while (bid >= p.cum[seg + 1]) ++seg;
    const TDesc d = p.d[seg];
    const int t = bid - p.cum[seg];
    const int n0 = (t % d.ntx) * 32, k0 = (t / d.ntx) * 32;
    const int tx = threadIdx.x, ty = threadIdx.y;
#pragma unroll
    for (int i = 0; i < 32; i += 8)
        tile[ty + i][tx] = d.src[(size_t)(k0 + ty + i) * d.N + n0 + tx];
    __syncthreads();
#pragma unroll
    for (int i = 0; i < 32; i += 8)
        d.dst[(size_t)(n0 + ty + i) * d.K + k0 + tx] = f2bf(tile[tx][ty + i]);
}

// ---------------------------------------------------------------------------
// V [BH][S][DH] bf16 -> VT [BH][DH][S] bf16 (64-s tiles)
// ---------------------------------------------------------------------------
__global__ __launch_bounds__(256) void transpose_v(
    const unsigned short* __restrict__ V, unsigned short* __restrict__ VT)
{
    __shared__ unsigned short t[64][72];
    const int bh = blockIdx.y, s0 = blockIdx.x * 64;
    const int tid = threadIdx.x;
#pragma unroll
    for (int i = 0; i < 2; i++) {
        int u = tid + i * 256;
        int s = u >> 3, dc = u & 7;
        uint4 v = *(const uint4*)(V + ((size_t)bh * S_ + s0 + s) * DH_ + dc * 8);
        *(uint4*)&t[s][dc * 8] = v;
    }
    __syncthreads();
    const int dh = tid >> 2, sc = (tid & 3) * 16;
    unsigned v[16];
#pragma unroll
    for (int j = 0; j < 16; j++) v[j] = t[sc + j][dh];
    uint4 o0, o1;
    o0.x = v[0] | (v[1] << 16);  o0.y = v[2] | (v[3] << 16);
    o0.z = v[4] | (v[5] << 16);  o0.w = v[6] | (v[7] << 16);
    o1.x = v[8] | (v[9] << 16);  o1.y = v[10] | (v[11] << 16);
    o1.z = v[12] | (v[13] << 16); o1.w = v[14] | (v[15] << 16);
    unsigned short* dst = VT + ((size_t)bh * DH_ + dh) * S_ + s0 + sc;
    *(uint4*)dst = o0;
    *(uint4*)(dst + 8) = o1;
}

// ---------------------------------------------------------------------------
// x0: f32 -> (f32 copy, bf16 copy)
// ---------------------------------------------------------------------------
__global__ __launch_bounds__(256) void cvt_x0(
    const float* __restrict__ in, float* __restrict__ xf, unsigned short* __restrict__ xh)
{
    int i = blockIdx.x * 256 + threadIdx.x;
    float4 v = ((const float4*)in)[i];
    ((float4*)xf)[i] = v;
    uint2 h;
    h.x = (unsigned)f2bf(v.x) | ((unsigned)f2bf(v.y) << 16);
    h.y = (unsigned)f2bf(v.z) | ((unsigned)f2bf(v.w) << 16);
    ((uint2*)xh)[i] = h;
}

// ---------------------------------------------------------------------------
// Unified GEMM: 128x128 tile, BK=64, XOR-swizzled LDS, optional split-K.
//  EPI 0: bf16 partial (no bias) -> outH + z*M*N   [split-K, reduced in LN]
//  EPI 1: bf16 + bias + relu -> outH               [FFN1]
//  EPI 2: QKV scatter to [B,H,S,DH] bf16, Q pre-scaled by log2e/8
// ---------------------------------------------------------------------------
template <int EPI, int KSPLIT>
__global__ __launch_bounds__(256) void gemm128(
    const unsigned short* __restrict__ A, const unsigned short* __restrict__ BT,
    int M, int N, int K,
    const float* __restrict__ b0, const float* __restrict__ b1, const float* __restrict__ b2,
    unsigned short* __restrict__ outH,
    unsigned short* __restrict__ qO, unsigned short* __restrict__ kO, unsigned short* __restrict__ vO)
{
    __shared__ __align__(16) unsigned short As[128 * 64];   // 16 KB
    __shared__ __align__(16) unsigned short Bs[128 * 64];   // 16 KB

    const int tid = threadIdx.x;
    const int m0 = blockIdx.y * 128, n0 = blockIdx.x * 128;
    const int kchunk = K / KSPLIT;
    const int kbase = (KSPLIT > 1) ? (int)blockIdx.z * kchunk : 0;
    const int lane = tid & 63, wv = tid >> 6;
    const int wm = wv & 1, wn = wv >> 1;
    const int cl = lane & 15, quad = lane >> 4;

    // staging: thread t -> rows (t>>3)+32i, slot t&7, global chunk slot^(row&7)
    const int srow = tid >> 3, sslot = tid & 7;
    const int schk = sslot ^ (srow & 7);
    const unsigned short* gA = A  + (size_t)(m0 + srow) * K + kbase + schk * 8;
    const unsigned short* gB = BT + (size_t)(n0 + srow) * K + kbase + schk * 8;

    floatx4 acc[4][4];
#pragma unroll
    for (int i = 0; i < 4; i++)
#pragma unroll
        for (int j = 0; j < 4; j++) acc[i][j] = (floatx4){0.f, 0.f, 0.f, 0.f};

    for (int kt = 0; kt < kchunk; kt += 64) {
#pragma unroll
        for (int i = 0; i < 4; i++) {
            gl_lds16(gA + (size_t)(32 * i) * K + kt, &As[(size_t)(tid + 256 * i) * 8]);
            gl_lds16(gB + (size_t)(32 * i) * K + kt, &Bs[(size_t)(tid + 256 * i) * 8]);
        }
        __syncthreads();

        bf16x8 av[4][2], bv[4][2];
#pragma unroll
        for (int mi = 0; mi < 4; mi++) {
            const int row = wm * 64 + mi * 16 + cl;
#pragma unroll
            for (int ks = 0; ks < 2; ks++)
                av[mi][ks] = *(const bf16x8*)&As[row * 64 + (((ks * 4 + quad) ^ (cl & 7)) * 8)];
        }
#pragma unroll
        for (int ni = 0; ni < 4; ni++) {
            const int row = wn * 64 + ni * 16 + cl;
#pragma unroll
            for (int ks = 0; ks < 2; ks++)
                bv[ni][ks] = *(const bf16x8*)&Bs[row * 64 + (((ks * 4 + quad) ^ (cl & 7)) * 8)];
        }
#pragma unroll
        for (int mi = 0; mi < 4; mi++)
#pragma unroll
            for (int ni = 0; ni < 4; ni++) {
                acc[mi][ni] = __builtin_amdgcn_mfma_f32_16x16x32_bf16(
                    av[mi][0], bv[ni][0], acc[mi][ni], 0, 0, 0);
                acc[mi][ni] = __builtin_amdgcn_mfma_f32_16x16x32_bf16(
                    av[mi][1], bv[ni][1], acc[mi][ni], 0, 0, 0);
            }
        __syncthreads();
    }

    unsigned short* outHz = outH;
    if (EPI == 0 && KSPLIT > 1) outHz = outH + (size_t)blockIdx.z * M * N;
#pragma unroll
    for (int mi = 0; mi < 4; mi++) {
#pragma unroll
        for (int ni = 0; ni < 4; ni++) {
            const int c = n0 + wn * 64 + ni * 16 + cl;
#pragma unroll
            for (int r = 0; r < 4; r++) {
                const int rr = m0 + wm * 64 + mi * 16 + quad * 4 + r;
                float v = acc[mi][ni][r];
                if (EPI == 0) {
                    outHz[(size_t)rr * N + c] = f2bf(v);  // bf16 partial, bias in LN
                } else if (EPI == 1) {
                    float t = v + b0[c];
                    outH[(size_t)rr * N + c] = f2bf(t > 0.f ? t : 0.f);
                } else {
                    const int kind = c >> 10, cc = c & 1023;
                    const float* bp = (kind == 0) ? b0 : (kind == 1) ? b1 : b2;
                    float t = v + bp[cc];
                    if (kind == 0) t *= 0.18033688f;   // log2e / 8
                    const int h = cc >> 6, dh = cc & 63;
                    const int bb = rr >> 11, s = rr & 2047;
                    unsigned short* dst = (kind == 0) ? qO : (kind == 1) ? kO : vO;
                    dst[((size_t)(bb * H_ + h) * S_ + s) * DH_ + dh] = f2bf(t);
                }
            }
        }
    }
}

// ---------------------------------------------------------------------------
// Flash attention v5: S^T orientation, single-pass softmax, K-tile = 128.
// R4's two-barrier single-buffer structure (hoisted loop-invariant LDS
// offsets — R5 showed buffer-muxing costs more VALU than barriers save),
// with barrier count halved: 16 k-tiles of 128 instead of 32 of 64.
// Per tile/wave: 16 QK MFMA + 32 PV MFMA + 32 exp2.
// ---------------------------------------------------------------------------
__global__ __launch_bounds__(256) void attn_kernel(
    const unsigned short* __restrict__ Qg, const unsigned short* __restrict__ Kg,
    const unsigned short* __restrict__ VTg, unsigned short* __restrict__ ctx)
{
    __shared__ __align__(16) unsigned short Ks[128 * 64];  // [kcol][dh] swizzled, 16 KB
    __shared__ __align__(16) unsigned short Vs[64 * 128];  // [dh][kcol] swizzled, 16 KB

    const int tid = threadIdx.x, lane = tid & 63, wv = tid >> 6;
    const int cl = lane & 15, quad = lane >> 4;

    // XCD-aware mapping: same-XCD blocks share 4 bh -> KV fits that XCD's L2
    const int lin = blockIdx.x;
    const int idx = lin >> 3;
    const int bh  = (lin & 7) * 4 + (idx & 3);
    const int qt  = idx >> 2;
    const int qrow = qt * 64 + wv * 16 + cl;
    const size_t bhS = (size_t)bh * S_;

    bf16x8 aq[2];
#pragma unroll
    for (int ks = 0; ks < 2; ks++)
        aq[ks] = *(const bf16x8*)(Qg + (bhS + qrow) * DH_ + ks * 32 + quad * 8);

    floatx4 O[4];
#pragma unroll
    for (int i = 0; i < 4; i++) O[i] = (floatx4){0.f, 0.f, 0.f, 0.f};
    float l_cur = 0.f;

    // staging base pointers (4 granules each of K and V per thread)
    const unsigned short* kp[4];
    const unsigned short* vp[4];
#pragma unroll
    for (int i = 0; i < 4; i++) {
        const int g = tid + 256 * i;
        const int kr = g >> 3, ksl = g & 7, kch = ksl ^ (kr & 7);
        kp[i] = Kg + (bhS + kr) * DH_ + kch * 8;
        const int vr = g >> 4, vsl = g & 15, vch = vsl ^ (vr & 7);
        vp[i] = VTg + ((size_t)bh * DH_ + vr) * S_ + vch * 8;
    }

    // tile-invariant fragment offsets (single buffer -> fully hoisted)
    int koff0[8], koff1[8], voff[8][4];
#pragma unroll
    for (int mi = 0; mi < 8; mi++) {
        const int row = mi * 16 + cl;
        koff0[mi] = (row * 8 + (quad       ^ (cl & 7))) * 8;
        koff1[mi] = (row * 8 + ((4 + quad) ^ (cl & 7))) * 8;
    }
#pragma unroll
    for (int c16 = 0; c16 < 8; c16++)
#pragma unroll
        for (int mi2 = 0; mi2 < 4; mi2++) {
            const int row = mi2 * 16 + cl;
            const int slot = (c16 * 2 + (quad >> 1)) ^ (cl & 7);
            voff[c16][mi2] = (row * 16 + slot) * 8 + (quad & 1) * 4;
        }

    for (int k0 = 0; k0 < S_; k0 += 128) {
        __syncthreads();   // all waves done reading previous tile
#pragma unroll
        for (int i = 0; i < 4; i++) {
            const int g = tid + 256 * i;
            gl_lds16(kp[i] + (size_t)k0 * DH_, &Ks[(size_t)g * 8]);
            gl_lds16(vp[i] + k0,               &Vs[(size_t)g * 8]);
        }
        __syncthreads();

        // ---- St = K·Q^T : sc[mi][r] = score(k = k0+mi*16+quad*4+r, q = qrow)
        floatx4 sc[8];
#pragma unroll
        for (int mi = 0; mi < 8; mi++) {
            bf16x8 kf0 = *(const bf16x8*)&Ks[koff0[mi]];
            bf16x8 kf1 = *(const bf16x8*)&Ks[koff1[mi]];
            floatx4 z = (floatx4){0.f, 0.f, 0.f, 0.f};
            z = __builtin_amdgcn_mfma_f32_16x16x32_bf16(kf0, aq[0], z, 0, 0, 0);
            sc[mi] = __builtin_amdgcn_mfma_f32_16x16x32_bf16(kf1, aq[1], z, 0, 0, 0);
        }

        // ---- single-pass softmax numerator: p = exp2(s); l accumulates per-lane
        int pk[8][2];
#pragma unroll
        for (int mi = 0; mi < 8; mi++) {
            float p0 = __builtin_amdgcn_exp2f(sc[mi][0]);
            float p1 = __builtin_amdgcn_exp2f(sc[mi][1]);
            float p2 = __builtin_amdgcn_exp2f(sc[mi][2]);
            float p3 = __builtin_amdgcn_exp2f(sc[mi][3]);
            l_cur += (p0 + p1) + (p2 + p3);
            pk[mi][0] = packbf(p0, p1);
            pk[mi][1] = packbf(p2, p3);
        }

        // ---- PV: O[dh][q] += V^T · P   (p fed straight from registers)
#pragma unroll
        for (int c16 = 0; c16 < 8; c16++) {
            union { int i[2]; short4v s; } pb;
            pb.i[0] = pk[c16][0];
            pb.i[1] = pk[c16][1];
#pragma unroll
            for (int mi2 = 0; mi2 < 4; mi2++) {
                short4v va = *(const short4v*)&Vs[voff[c16][mi2]];
                O[mi2] = __builtin_amdgcn_mfma_f32_16x16x16bf16_1k(va, pb.s, O[mi2], 0, 0, 0);
            }
        }
    }

    // final cross-quad reduction of l (lanes with same cl share the q row)
    l_cur += __shfl_xor(l_cur, 16);
    l_cur += __shfl_xor(l_cur, 32);

    const float invl = 1.f / l_cur;
    const int b = bh >> 4, h = bh & 15;
    unsigned short* cp = ctx + ((size_t)(b * S_ + qrow)) * D_ + h * DH_ + quad * 4;
#pragma unroll
    for (int mi2 = 0; mi2 < 4; mi2++) {
        unsigned short w[4];
#pragma unroll
        for (int r = 0; r < 4; r++) w[r] = f2bf(O[mi2][r] * invl);
        unsigned o0 = (unsigned)w[0] | ((unsigned)w[1] << 16);
        unsigned o1 = (unsigned)w[2] | ((unsigned)w[3] << 16);
        uint2 ov; ov.x = o0; ov.y = o1;
        *(uint2*)(cp + mi2 * 16) = ov;
    }
}

// ---------------------------------------------------------------------------
// Fused split-K reduce (bf16 partials) + bias + residual + LayerNorm.
// ---------------------------------------------------------------------------
template <int NP>
__global__ __launch_bounds__(256) void ln_kernel(
    const unsigned short* __restrict__ ph, const float* __restrict__ bias,
    const float* __restrict__ xr,
    const float* __restrict__ g, const float* __restrict__ b,
    float* __restrict__ xf, unsigned short* __restrict__ xh, float* __restrict__ extra)
{
    const int row = blockIdx.x, tid = threadIdx.x;
    float4 a = {0.f, 0.f, 0.f, 0.f};
#pragma unroll
    for (int p = 0; p < NP; p++) {
        const uint2 hv = ((const uint2*)(ph + (size_t)p * M_ * D_ + (size_t)row * D_))[tid];
        a.x += __uint_as_float(hv.x << 16);
        a.y += __uint_as_float(hv.x & 0xFFFF0000u);
        a.z += __uint_as_float(hv.y << 16);
        a.w += __uint_as_float(hv.y & 0xFFFF0000u);
    }
    const float4 bs = ((const float4*)bias)[tid];
    const float4 c = ((const float4*)(xr + (size_t)row * D_))[tid];
    float4 y;
    y.x = a.x + bs.x + c.x; y.y = a.y + bs.y + c.y;
    y.z = a.z + bs.z + c.z; y.w = a.w + bs.w + c.w;
    float s  = y.x + y.y + y.z + y.w;
    float sq = y.x * y.x + y.y * y.y + y.z * y.z + y.w * y.w;
#pragma unroll
    for (int off = 1; off < 64; off <<= 1) {
        s  += __shfl_xor(s, off);
        sq += __shfl_xor(sq, off);
    }
    __shared__ float red[8];
    const int wv = tid >> 6, lane = tid & 63;
    if (lane == 0) { red[wv] = s; red[4 + wv] = sq; }
    __syncthreads();
    s  = red[0] + red[1] + red[2] + red[3];
    sq = red[4] + red[5] + red[6] + red[7];
    const float mean = s * (1.f / D_);
    const float var  = sq * (1.f / D_) - mean * mean;
    const float ri   = rsqrtf(var + 1e-6f);
    const float4 gg = ((const float4*)g)[tid];
    const float4 bb = ((const float4*)b)[tid];
    float4 o;
    o.x = (y.x - mean) * ri * gg.x + bb.x;
    o.y = (y.y - mean) * ri * gg.y + bb.y;
    o.z = (y.z - mean) * ri * gg.z + bb.z;
    o.w = (y.w - mean) * ri * gg.w + bb.w;
    ((float4*)(xf + (size_t)row * D_))[tid] = o;
    uint2 h;
    h.x = (unsigned)f2bf(o.x) | ((unsigned)f2bf(o.y) << 16);
    h.y = (unsigned)f2bf(o.z) | ((unsigned)f2bf(o.w) << 16);
    ((uint2*)(xh + (size_t)row * D_))[tid] = h;
    if (extra) ((float4*)(extra + (size_t)row * D_))[tid] = o;
}

// ---------------------------------------------------------------------------
extern "C" void kernel_launch(void* const* d_in, const int* in_sizes, int n_in,
                              void* d_out, int out_size, void* d_ws, size_t ws_size,
                              hipStream_t stream)
{
    const float* hs  = (const float*)d_in[0];
    const float* Wq  = (const float*)d_in[1];
    const float* bq  = (const float*)d_in[2];
    const float* Wk  = (const float*)d_in[3];
    const float* bk  = (const float*)d_in[4];
    const float* Wv  = (const float*)d_in[5];
    const float* bv  = (const float*)d_in[6];
    const float* Wp  = (const float*)d_in[7];
    const float* bp  = (const float*)d_in[8];
    const float* g1  = (const float*)d_in[9];
    const float* be1 = (const float*)d_in[10];
    const float* W1  = (const float*)d_in[11];
    const float* b1  = (const float*)d_in[12];
    const float* W2  = (const float*)d_in[13];
    const float* b2  = (const float*)d_in[14];
    const float* g2  = (const float*)d_in[15];
    const float* be2 = (const float*)d_in[16];

    char* w = (char*)d_ws;
    auto alloc = [&](size_t bytes) { char* p = w; w += (bytes + 255) & ~(size_t)255; return p; };
    unsigned short* wqkvT = (unsigned short*)alloc(3072ull * 1024 * 2);
    unsigned short* wpT   = (unsigned short*)alloc(1024ull * 1024 * 2);
    unsigned short* w1T   = (unsigned short*)alloc(4096ull * 1024 * 2);
    unsigned short* w2T   = (unsigned short*)alloc(1024ull * 4096 * 2);
    float*          xf    = (float*)alloc(4096ull * 1024 * 4);
    unsigned short* xh    = (unsigned short*)alloc(4096ull * 1024 * 2);
    unsigned short* qb_   = (unsigned short*)alloc(4096ull * 1024 * 2);
    unsigned short* kb_   = (unsigned short*)alloc(4096ull * 1024 * 2);
    unsigned short* vb_   = (unsigned short*)alloc(4096ull * 1024 * 2);
    unsigned short* ctx   = (unsigned short*)alloc(4096ull * 1024 * 2);
    unsigned short* part  = (unsigned short*)alloc(4ull * 4096 * 1024 * 2); // 4 bf16 partials
    unsigned short* hh    = (unsigned short*)alloc(4096ull * 4096 * 2);
    unsigned short* vtb   = hh;                 // V^T scratch (hh free during attn)

    const dim3 blk(256);
    const dim3 tb(32, 8);

    cvt_x0<<<4096, blk, 0, stream>>>(hs, xf, xh);

    for (int l = 0; l < 4; l++) {
        // --- all 6 weight transposes in one launch ---
        TPack tp;
        tp.d[0] = { Wq + (size_t)l * D_ * D_,  wqkvT,                   D_,  D_,  32 };
        tp.d[1] = { Wk + (size_t)l * D_ * D_,  wqkvT + 1024 * 1024,     D_,  D_,  32 };
        tp.d[2] = { Wv + (size_t)l * D_ * D_,  wqkvT + 2 * 1024 * 1024, D_,  D_,  32 };
        tp.d[3] = { Wp + (size_t)l * D_ * D_,  wpT,                     D_,  D_,  32 };
        tp.d[4] = { W1 + (size_t)l * D_ * FF_, w1T,                     D_,  FF_, 128 };
        tp.d[5] = { W2 + (size_t)l * FF_ * D_, w2T,                     FF_, D_,  32 };
        tp.cum[0] = 0;    tp.cum[1] = 1024; tp.cum[2] = 2048; tp.cum[3] = 3072;
        tp.cum[4] = 4096; tp.cum[5] = 8192; tp.cum[6] = 12288;
        transpose_cvt_batch<<<12288, tb, 0, stream>>>(tp);

        // QKV: N=3072, K=1024
        gemm128<2, 1><<<dim3(24, 32), blk, 0, stream>>>(xh, wqkvT, M_, 3 * D_, D_,
            bq + l * D_, bk + l * D_, bv + l * D_,
            nullptr, qb_, kb_, vb_);

        transpose_v<<<dim3(32, 32), blk, 0, stream>>>(vb_, vtb);

        attn_kernel<<<1024, blk, 0, stream>>>(qb_, kb_, vtb, ctx);

        // proj: N=1024, K=1024, split-K x2 -> bf16 partials, reduced in LN1
        gemm128<0, 2><<<dim3(8, 32, 2), blk, 0, stream>>>(ctx, wpT, M_, D_, D_,
            nullptr, nullptr, nullptr, part, nullptr, nullptr, nullptr);

        ln_kernel<2><<<4096, blk, 0, stream>>>(part, bp + l * D_, xf,
            g1 + l * D_, be1 + l * D_, xf, xh, nullptr);

        // FFN1: N=4096, K=1024
        gemm128<1, 1><<<dim3(32, 32), blk, 0, stream>>>(xh, w1T, M_, FF_, D_,
            b1 + l * FF_, nullptr, nullptr, hh, nullptr, nullptr, nullptr);

        // FFN2: N=1024, K=4096, split-K x4 -> bf16 partials, reduced in LN2
        gemm128<0, 4><<<dim3(8, 32, 4), blk, 0, stream>>>(hh, w2T, M_, D_, FF_,
            nullptr, nullptr, nullptr, part, nullptr, nullptr, nullptr);

        ln_kernel<4><<<4096, blk, 0, stream>>>(part, b2 + l * D_, xf,
            g2 + l * D_, be2 + l * D_, xf, xh,
            (l == 3) ? (float*)d_out : nullptr);
    }
}